// Round 1
// baseline (614.549 us; speedup 1.0000x reference)
//
#include <hip/hip_runtime.h>
#include <hip/hip_bf16.h>
#include <cstdint>

typedef __bf16 bf16_t;
typedef __attribute__((ext_vector_type(8))) __bf16 bf16x8;
typedef __attribute__((ext_vector_type(4))) __bf16 bf16x4;
typedef __attribute__((ext_vector_type(4))) float f32x4;

#define NEXP 8
#define NTOK 4096
#define DK   2048
#define DN   2816
#define DN2  5632
#define NP   8192
#define PPE  1024

// ---------- fp32 -> bf16 convert with per-expert concat placement ----------
__global__ void k_convert(const float* __restrict__ src, bf16_t* __restrict__ dst,
                          int perExp4, long dstStride, long dstOff, int total4) {
    int stride = gridDim.x * blockDim.x;
    for (int i = blockIdx.x * blockDim.x + threadIdx.x; i < total4; i += stride) {
        int e  = i / perExp4;
        int r4 = i - e * perExp4;
        float4 v = reinterpret_cast<const float4*>(src)[i];
        bf16x4 o = { (bf16_t)v.x, (bf16_t)v.y, (bf16_t)v.z, (bf16_t)v.w };
        *reinterpret_cast<bf16x4*>(dst + (long)e * dstStride + dstOff + (long)r4 * 4) = o;
    }
}

// ---------- gather x rows by sorted_token_ids, convert to bf16 ----------
__global__ void k_gather(const float* __restrict__ x, const int* __restrict__ ids,
                         bf16_t* __restrict__ xg) {
    int i = blockIdx.x * blockDim.x + threadIdx.x;
    if (i >= NP * (DK / 4)) return;
    int p  = i >> 9;          // / (DK/4)=512
    int c4 = i & 511;
    int tok = ids[p];
    float4 v = reinterpret_cast<const float4*>(x + (size_t)tok * DK)[c4];
    bf16x4 o = { (bf16_t)v.x, (bf16_t)v.y, (bf16_t)v.z, (bf16_t)v.w };
    *reinterpret_cast<bf16x4*>(xg + (size_t)p * DK + c4 * 4) = o;
}

// ---------- h = sigmoid(gate) * up, written in-place into gate half ----------
__global__ void k_act(bf16_t* __restrict__ gu) {
    int i = blockIdx.x * blockDim.x + threadIdx.x;
    if (i >= NP * (DN / 8)) return;
    int p = i / (DN / 8);
    int c = i - p * (DN / 8);
    bf16_t* row = gu + (size_t)p * DN2 + c * 8;
    bf16x8 g = *reinterpret_cast<const bf16x8*>(row);
    bf16x8 u = *reinterpret_cast<const bf16x8*>(row + DN);
    bf16x8 h;
#pragma unroll
    for (int j = 0; j < 8; ++j) {
        float gf = (float)g[j], uf = (float)u[j];
        float s = 1.0f / (1.0f + __expf(-gf));
        h[j] = (bf16_t)(s * uf);
    }
    *reinterpret_cast<bf16x8*>(row) = h;
}

// ---------- async global->LDS, 16B per lane ----------
__device__ __forceinline__ void gl2lds16(const bf16_t* g, bf16_t* l) {
    __builtin_amdgcn_global_load_lds(
        (__attribute__((address_space(1))) void*)(const_cast<bf16_t*>(g)),
        (__attribute__((address_space(3))) void*)(l), 16, 0, 0);
}

// ---------- BT GEMM: C[m,n] = sum_k A[m,k]*B[n,k], per-expert panels ----------
// EPI=0: store bf16 into Cb.  EPI=1: scale by tw[pair], atomicAdd scatter into Cf.
template <int EPI>
__launch_bounds__(256, 2)
__global__ void k_gemm(const bf16_t* __restrict__ A, const bf16_t* __restrict__ B,
                       bf16_t* __restrict__ Cb, float* __restrict__ Cf,
                       const float* __restrict__ tw, const int* __restrict__ ids,
                       int Mtiles, int Ntiles, int Kd, int lda, int ldb,
                       long aStride, long bStride, int ldc, long cStride) {
    __shared__ bf16_t As[128 * 64];
    __shared__ bf16_t Bs[128 * 64];
    const int tpe = Mtiles * Ntiles;
    const int e  = blockIdx.x / tpe;
    const int r  = blockIdx.x - e * tpe;
    const int mt = r / Ntiles;
    const int nt = r - mt * Ntiles;
    const bf16_t* Ae = A + (long)e * aStride + (long)mt * 128 * lda;
    const bf16_t* Be = B + (long)e * bStride + (long)nt * 128 * ldb;
    const int wid  = threadIdx.x >> 6;
    const int lane = threadIdx.x & 63;
    const int wr = wid >> 1, wc = wid & 1;     // 2x2 wave grid, 64x64 per wave
    const int lr = lane & 15;                  // frag row
    const int lk = (lane >> 4) * 8;            // frag k offset
    const int srow = wid * 32 + (lane >> 3);   // staging row
    const int scol = (lane & 7) * 8;           // staging col (8 bf16 = 16B)

    f32x4 acc[4][4];
#pragma unroll
    for (int a = 0; a < 4; ++a)
#pragma unroll
        for (int b = 0; b < 4; ++b) acc[a][b] = (f32x4){0.f, 0.f, 0.f, 0.f};

    const int kTiles = Kd >> 6;
    for (int kt = 0; kt < kTiles; ++kt) {
        __syncthreads();  // previous iter's reads done before overwriting LDS
        const bf16_t* ap = Ae + kt * 64 + scol;
        const bf16_t* bp = Be + kt * 64 + scol;
#pragma unroll
        for (int j = 0; j < 4; ++j) {
            gl2lds16(ap + (long)(srow + j * 8) * lda, &As[(wid * 32 + j * 8) * 64]);
            gl2lds16(bp + (long)(srow + j * 8) * ldb, &Bs[(wid * 32 + j * 8) * 64]);
        }
        __syncthreads();  // compiler drains vmcnt before this barrier
#pragma unroll
        for (int kk = 0; kk < 2; ++kk) {
            bf16x8 af[4], bfr[4];
#pragma unroll
            for (int mi = 0; mi < 4; ++mi)
                af[mi] = *reinterpret_cast<const bf16x8*>(
                    &As[(wr * 64 + mi * 16 + lr) * 64 + kk * 32 + lk]);
#pragma unroll
            for (int ni = 0; ni < 4; ++ni)
                bfr[ni] = *reinterpret_cast<const bf16x8*>(
                    &Bs[(wc * 64 + ni * 16 + lr) * 64 + kk * 32 + lk]);
#pragma unroll
            for (int mi = 0; mi < 4; ++mi)
#pragma unroll
                for (int ni = 0; ni < 4; ++ni)
                    acc[mi][ni] = __builtin_amdgcn_mfma_f32_16x16x32_bf16(
                        af[mi], bfr[ni], acc[mi][ni], 0, 0, 0);
        }
    }

    const int orow0 = wr * 64 + (lane >> 4) * 4;  // C/D: row=(l>>4)*4+i
    const int ocol0 = wc * 64 + (lane & 15);      //      col=l&15
    if constexpr (EPI == 0) {
        bf16_t* Ce = Cb + (long)e * cStride + (long)mt * 128 * ldc + (long)nt * 128;
#pragma unroll
        for (int mi = 0; mi < 4; ++mi)
#pragma unroll
            for (int i = 0; i < 4; ++i) {
                int row = orow0 + mi * 16 + i;
#pragma unroll
                for (int ni = 0; ni < 4; ++ni)
                    Ce[(long)row * ldc + ocol0 + ni * 16] = (bf16_t)acc[mi][ni][i];
            }
    } else {
        const int p0 = e * PPE + mt * 128;
#pragma unroll
        for (int mi = 0; mi < 4; ++mi)
#pragma unroll
            for (int i = 0; i < 4; ++i) {
                int gp  = p0 + orow0 + mi * 16 + i;
                float w = tw[gp];
                float* orow = Cf + (size_t)ids[gp] * DK + nt * 128 + ocol0;
#pragma unroll
                for (int ni = 0; ni < 4; ++ni)
                    atomicAdd(&orow[ni * 16], acc[mi][ni][i] * w);
            }
    }
}

extern "C" void kernel_launch(void* const* d_in, const int* in_sizes, int n_in,
                              void* d_out, int out_size, void* d_ws, size_t ws_size,
                              hipStream_t stream) {
    const float* x   = (const float*)d_in[0];
    const float* W1  = (const float*)d_in[1];
    const float* W3  = (const float*)d_in[2];
    const float* W2  = (const float*)d_in[3];
    const float* tw  = (const float*)d_in[4];
    const int*   sid = (const int*)d_in[5];
    float* out = (float*)d_out;

    // workspace layout (384 MB total)
    char* ws = (char*)d_ws;
    bf16_t* w13b = (bf16_t*)ws;                                        // [E][2N][K] bf16: 176MB
    bf16_t* w2b  = (bf16_t*)(ws + 184549376L);                         // [E][K][N]  bf16:  88MB
    bf16_t* xg   = (bf16_t*)(ws + 184549376L + 92274688L);             // [P][K]     bf16:  32MB
    bf16_t* gu   = (bf16_t*)(ws + 184549376L + 92274688L + 33554432L); // [P][2N]    bf16:  88MB

    hipMemsetAsync(d_out, 0, (size_t)out_size * sizeof(float), stream);

    const int per4 = DN * DK / 4;        // elems/expert / 4
    const int tot4 = NEXP * per4;
    k_convert<<<2048, 256, 0, stream>>>(W1, w13b, per4, (long)DN2 * DK, 0L, tot4);
    k_convert<<<2048, 256, 0, stream>>>(W3, w13b, per4, (long)DN2 * DK, (long)DN * DK, tot4);
    k_convert<<<2048, 256, 0, stream>>>(W2, w2b, per4, (long)DK * DN, 0L, tot4);
    k_gather<<<NP * (DK / 4) / 256, 256, 0, stream>>>(x, sid, xg);

    // GEMM1: gu[e,p,0:5632] = xg[e,p,:] . w13b[e,n,:]^T
    k_gemm<0><<<NEXP * 8 * 44, 256, 0, stream>>>(
        xg, w13b, gu, nullptr, nullptr, nullptr,
        8, 44, DK, DK, DK, (long)PPE * DK, (long)DN2 * DK, DN2, (long)PPE * DN2);

    // h (in place into gate half of gu)
    k_act<<<NP * (DN / 8) / 256, 256, 0, stream>>>(gu);

    // GEMM2: out[tok, k] += tw[p] * h[e,p,:] . w2b[e,k,:]^T
    k_gemm<1><<<NEXP * 8 * 16, 256, 0, stream>>>(
        gu, w2b, nullptr, out, tw, sid,
        8, 16, DN, DN2, DN, (long)PPE * DN2, (long)DK * DN, 0, 0L);
}

// Round 2
// 507.782 us; speedup vs baseline: 1.2103x; 1.2103x over previous
//
#include <hip/hip_runtime.h>
#include <hip/hip_bf16.h>
#include <cstdint>

typedef __bf16 bf16_t;
typedef __attribute__((ext_vector_type(8))) __bf16 bf16x8;
typedef __attribute__((ext_vector_type(4))) __bf16 bf16x4;
typedef __attribute__((ext_vector_type(4))) float f32x4;

#define NEXP 8
#define DK   2048
#define DN   2816
#define DN2  5632
#define NP   8192
#define PPE  1024

// ---------- flat fp32 -> bf16 ----------
__global__ void k_cvt(const float* __restrict__ src, bf16_t* __restrict__ dst, int total4) {
    int stride = gridDim.x * blockDim.x;
    for (int i = blockIdx.x * blockDim.x + threadIdx.x; i < total4; i += stride) {
        float4 v = reinterpret_cast<const float4*>(src)[i];
        bf16x4 o = { (bf16_t)v.x, (bf16_t)v.y, (bf16_t)v.z, (bf16_t)v.w };
        reinterpret_cast<bf16x4*>(dst)[i] = o;
    }
}

// ---------- W1/W3 -> interleaved [E][5632][K]: 16-row groups alternate gate/up ----------
// W1 row n -> 32*(n>>4) + (n&15) + rowAdd(0);  W3 -> +16
__global__ void k_cvt_w13(const float* __restrict__ src, bf16_t* __restrict__ dst, int rowAdd) {
    int stride = gridDim.x * blockDim.x;
    const int total4 = NEXP * DN * (DK / 4);
    for (int i = blockIdx.x * blockDim.x + threadIdx.x; i < total4; i += stride) {
        int g  = i >> 9;           // source row (K/4 = 512 vec4 per row)
        int c4 = i & 511;
        int e  = g / DN;
        int n  = g - e * DN;
        long drow = (long)e * DN2 + ((n >> 4) << 5) + (n & 15) + rowAdd;
        float4 v = reinterpret_cast<const float4*>(src)[i];
        bf16x4 o = { (bf16_t)v.x, (bf16_t)v.y, (bf16_t)v.z, (bf16_t)v.w };
        *reinterpret_cast<bf16x4*>(dst + drow * DK + c4 * 4) = o;
    }
}

// ---------- gather x rows by sorted_token_ids, convert to bf16 ----------
__global__ void k_gather(const float* __restrict__ x, const int* __restrict__ ids,
                         bf16_t* __restrict__ xg) {
    int i = blockIdx.x * blockDim.x + threadIdx.x;
    if (i >= NP * (DK / 4)) return;
    int p  = i >> 9;
    int c4 = i & 511;
    int tok = ids[p];
    float4 v = reinterpret_cast<const float4*>(x + (size_t)tok * DK)[c4];
    bf16x4 o = { (bf16_t)v.x, (bf16_t)v.y, (bf16_t)v.z, (bf16_t)v.w };
    *reinterpret_cast<bf16x4*>(xg + (size_t)p * DK + c4 * 4) = o;
}

// ---------- async global->LDS, 16B per lane (wave-uniform LDS base) ----------
__device__ __forceinline__ void gl2lds16(const bf16_t* g, bf16_t* l) {
    __builtin_amdgcn_global_load_lds(
        (__attribute__((address_space(1))) void*)(const_cast<bf16_t*>(g)),
        (__attribute__((address_space(3))) void*)(l), 16, 0, 0);
}

#define BARX() __builtin_amdgcn_s_barrier()
#define LGKM0() asm volatile("s_waitcnt lgkmcnt(0)" ::: "memory")
#define VMW4() asm volatile("s_waitcnt vmcnt(4)" ::: "memory")
#define VMW0() asm volatile("s_waitcnt vmcnt(0)" ::: "memory")

// stage one 128-row half-tile (2 x global_load_lds per thread, 16B each)
#define STG(ARR, SRC, LD, BUF, HALF, KT) do {                                   \
    gl2lds16((SRC) + (long)((HALF) * 128) * (LD) + (long)(KT) * 64,             \
             &ARR[BUF][(HALF) * 128 + w8][0]);                                  \
    gl2lds16((SRC) + (long)((HALF) * 128 + 64) * (LD) + (long)(KT) * 64,        \
             &ARR[BUF][(HALF) * 128 + 64 + w8][0]);                             \
} while (0)

#define LOADA(DST, BASE) do { _Pragma("unroll")                                 \
    for (int mi_ = 0; mi_ < 4; ++mi_) {                                         \
        DST[mi_][0] = *reinterpret_cast<const bf16x8*>((BASE) + aoff0 + mi_ * 1024); \
        DST[mi_][1] = *reinterpret_cast<const bf16x8*>((BASE) + aoff1 + mi_ * 1024); \
    } } while (0)

#define LOADB(DST, BASE) do { _Pragma("unroll")                                 \
    for (int ni_ = 0; ni_ < 2; ++ni_) {                                         \
        DST[ni_][0] = *reinterpret_cast<const bf16x8*>((BASE) + boff0 + ni_ * 1024); \
        DST[ni_][1] = *reinterpret_cast<const bf16x8*>((BASE) + boff1 + ni_ * 1024); \
    } } while (0)

#define MFMAQ(AF, BF, MIB, NIB) do {                                            \
    __builtin_amdgcn_s_setprio(1);                                              \
    _Pragma("unroll") for (int kk_ = 0; kk_ < 2; ++kk_)                         \
    _Pragma("unroll") for (int mi_ = 0; mi_ < 4; ++mi_)                         \
    _Pragma("unroll") for (int ni_ = 0; ni_ < 2; ++ni_)                         \
        acc[(MIB) + mi_][(NIB) + ni_] = __builtin_amdgcn_mfma_f32_16x16x32_bf16( \
            AF[mi_][kk_], BF[ni_][kk_], acc[(MIB) + mi_][(NIB) + ni_], 0, 0, 0); \
    __builtin_amdgcn_s_setprio(0);                                              \
} while (0)

// ---------- 256x256 8-phase BT GEMM, XOR-swizzled LDS ----------
// EPI=0: fused sigmoid(gate)*up epilogue (interleaved B), writes h bf16 [NP][DN].
// EPI=1: scale by tw[pair], atomicAdd scatter into out fp32 [NTOK][DK].
template <int EPI>
__launch_bounds__(512, 2)
__global__ void k_gemm(const bf16_t* __restrict__ A, const bf16_t* __restrict__ B,
                       bf16_t* __restrict__ Hout, float* __restrict__ Fout,
                       const float* __restrict__ tw, const int* __restrict__ ids,
                       int Mtiles, int Ntiles, int nkt, int lda, int ldb,
                       long aStride, long bStride) {
    __shared__ bf16_t As[2][256][64];
    __shared__ bf16_t Bs[2][256][64];

    // XCD-bijective swizzle (grid % 8 == 0): each XCD gets one contiguous chunk
    const int nwg = gridDim.x;
    const int logical = (blockIdx.x & 7) * (nwg >> 3) + (blockIdx.x >> 3);
    const int tpe = Mtiles * Ntiles;
    const int e  = logical / tpe;
    const int r  = logical - e * tpe;
    const int mt = r / Ntiles;
    const int nt = r - mt * Ntiles;

    const int tid  = threadIdx.x;
    const int w    = tid >> 6;
    const int w8   = w * 8;
    const int lane = tid & 63;
    const int wr = w >> 2, wc = w & 3;        // 2(M) x 4(N) wave grid, 128x64/wave
    const int fr = lane & 15;
    const int fc = lane >> 4;

    // staging source: pre-swizzled global chunk (involution: c' = c ^ (row&7))
    const int srow = tid >> 3;                 // 0..63
    const int schk = (tid & 7) ^ (srow & 7);
    const bf16_t* aSrc = A + (long)e * aStride + ((long)mt * 256 + srow) * lda + schk * 8;
    const bf16_t* bSrc = B + (long)e * bStride + ((long)nt * 256 + srow) * ldb + schk * 8;

    // ds_read element offsets (swizzled): row*64 + (chunk ^ (row&7))*8
    const int sx = lane & 7;
    const int aoff0 = (wr * 128 + fr) * 64 + ((0 + fc) ^ sx) * 8;  // kk=0
    const int aoff1 = (wr * 128 + fr) * 64 + ((4 + fc) ^ sx) * 8;  // kk=1
    const int boff0 = (wc * 64 + fr) * 64 + ((0 + fc) ^ sx) * 8;
    const int boff1 = (wc * 64 + fr) * 64 + ((4 + fc) ^ sx) * 8;

    const bf16_t* As0 = &As[0][0][0];
    const bf16_t* As1 = &As[1][0][0];
    const bf16_t* Bs0 = &Bs[0][0][0];
    const bf16_t* Bs1 = &Bs[1][0][0];

    f32x4 acc[8][4];
#pragma unroll
    for (int a = 0; a < 8; ++a)
#pragma unroll
        for (int b = 0; b < 4; ++b) acc[a][b] = (f32x4){0.f, 0.f, 0.f, 0.f};

    bf16x8 af[4][2], ah[4][2], bl[2][2], bh[2][2];

    // prologue: tile0 full -> buf0, tile1 B halves -> buf1
    STG(As, aSrc, lda, 0, 0, 0); STG(As, aSrc, lda, 0, 1, 0);
    STG(Bs, bSrc, ldb, 0, 0, 0); STG(Bs, bSrc, ldb, 0, 1, 0);
    STG(Bs, bSrc, ldb, 1, 0, 1); STG(Bs, bSrc, ldb, 1, 1, 1);
    VMW4();           // tile0's 8 loads landed (tile1 B may stay in flight)
    BARX();

    const int nIter = nkt >> 1;
    for (int it = 0; it < nIter; ++it) {
        const int t = it * 2;
        const bool last = (it == nIter - 1);
        // P1: buf0 a-lo,b-lo | stage buf1.A0(t+1)
        LOADA(af, As0); LOADB(bl, Bs0);
        STG(As, aSrc, lda, 1, 0, t + 1);
        BARX(); LGKM0();
        MFMAQ(af, bl, 0, 0);
        BARX();
        // P2: b-hi | stage buf1.A1(t+1)
        LOADB(bh, Bs0 + 2048);
        STG(As, aSrc, lda, 1, 1, t + 1);
        BARX(); LGKM0();
        MFMAQ(af, bh, 0, 2);
        BARX();
        // P3: a-hi | stage buf0.B0(t+2)
        LOADA(ah, As0 + 4096);
        if (!last) STG(Bs, bSrc, ldb, 0, 0, t + 2);
        BARX(); LGKM0();
        MFMAQ(ah, bh, 4, 2);
        BARX();
        // P4: stage buf0.B1(t+2) | counted vmcnt: tile t+1 fully landed
        if (!last) { STG(Bs, bSrc, ldb, 0, 1, t + 2); VMW4(); } else { VMW0(); }
        BARX();
        MFMAQ(ah, bl, 4, 0);
        BARX();
        // P5: buf1 a-lo,b-lo | stage buf0.A0(t+2)
        LOADA(af, As1); LOADB(bl, Bs1);
        if (!last) STG(As, aSrc, lda, 0, 0, t + 2);
        BARX(); LGKM0();
        MFMAQ(af, bl, 0, 0);
        BARX();
        // P6: b-hi | stage buf0.A1(t+2)
        LOADB(bh, Bs1 + 2048);
        if (!last) STG(As, aSrc, lda, 0, 1, t + 2);
        BARX(); LGKM0();
        MFMAQ(af, bh, 0, 2);
        BARX();
        // P7: a-hi | stage buf1.B0(t+3)
        LOADA(ah, As1 + 4096);
        if (!last) STG(Bs, bSrc, ldb, 1, 0, t + 3);
        BARX(); LGKM0();
        MFMAQ(ah, bh, 4, 2);
        BARX();
        // P8: stage buf1.B1(t+3) | counted vmcnt: tile t+2 fully landed
        if (!last) { STG(Bs, bSrc, ldb, 1, 1, t + 3); VMW4(); } else { VMW0(); }
        BARX();
        MFMAQ(ah, bl, 4, 0);
        BARX();
    }

    if constexpr (EPI == 0) {
        // interleaved cols: ni even = gate, ni odd = up (same real n)
        const long prow0 = (long)e * PPE + (long)mt * 256 + wr * 128 + fc * 4;
        const int col0 = nt * 128 + wc * 32 + fr;
#pragma unroll
        for (int mi = 0; mi < 8; ++mi)
#pragma unroll
            for (int i = 0; i < 4; ++i) {
                long row = prow0 + mi * 16 + i;
#pragma unroll
                for (int p = 0; p < 2; ++p) {
                    float g = acc[mi][2 * p][i];
                    float u = acc[mi][2 * p + 1][i];
                    float s = 1.f / (1.f + __expf(-g));
                    Hout[row * DN + col0 + p * 16] = (bf16_t)(s * u);
                }
            }
    } else {
        const int p0 = e * PPE + mt * 256 + wr * 128 + fc * 4;
        const int col0 = nt * 256 + wc * 64 + fr;
#pragma unroll
        for (int mi = 0; mi < 8; ++mi)
#pragma unroll
            for (int i = 0; i < 4; ++i) {
                int gp = p0 + mi * 16 + i;
                float wgt = tw[gp];
                float* ob = Fout + (long)ids[gp] * DK + col0;
#pragma unroll
                for (int ni = 0; ni < 4; ++ni)
                    atomicAdd(ob + ni * 16, acc[mi][ni][i] * wgt);
            }
    }
}

extern "C" void kernel_launch(void* const* d_in, const int* in_sizes, int n_in,
                              void* d_out, int out_size, void* d_ws, size_t ws_size,
                              hipStream_t stream) {
    const float* x   = (const float*)d_in[0];
    const float* W1  = (const float*)d_in[1];
    const float* W3  = (const float*)d_in[2];
    const float* W2  = (const float*)d_in[3];
    const float* tw  = (const float*)d_in[4];
    const int*   sid = (const int*)d_in[5];
    float* out = (float*)d_out;

    // workspace layout (~357 MB)
    char* ws = (char*)d_ws;
    bf16_t* w13i = (bf16_t*)ws;                      // [E][5632][2048] interleaved, 176MB
    bf16_t* w2b  = (bf16_t*)(ws + 184549376L);       // [E][2048][2816],             88MB
    bf16_t* xg   = (bf16_t*)(ws + 276824064L);       // [8192][2048],                32MB
    bf16_t* h    = (bf16_t*)(ws + 310378496L);       // [8192][2816],                44MB

    hipMemsetAsync(d_out, 0, (size_t)out_size * sizeof(float), stream);

    k_cvt_w13<<<2048, 256, 0, stream>>>(W1, w13i, 0);
    k_cvt_w13<<<2048, 256, 0, stream>>>(W3, w13i, 16);
    k_cvt<<<2048, 256, 0, stream>>>(W2, w2b, NEXP * DK * (DN / 4));
    k_gather<<<NP * (DK / 4) / 256, 256, 0, stream>>>(x, sid, xg);

    // GEMM1+act: h[p, n] = sigmoid(xg.W1^T) * (xg.W3^T), interleaved weights
    k_gemm<0><<<NEXP * 4 * 22, 512, 0, stream>>>(
        xg, w13i, h, nullptr, nullptr, nullptr,
        4, 22, 32, DK, DK, (long)PPE * DK, (long)DN2 * DK);

    // GEMM2: out[tok,k] += tw[p] * h[p,:] . w2b[e,k,:]^T
    k_gemm<1><<<NEXP * 4 * 8, 512, 0, stream>>>(
        h, w2b, nullptr, out, tw, sid,
        4, 8, 44, DN, DN, (long)PPE * DN, (long)DK * DN);
}